// Round 1
// baseline (880.205 us; speedup 1.0000x reference)
//
#include <hip/hip_runtime.h>
#include <math.h>

#define N_BATCH 128
#define C_DIM   512
#define BLKSZ   46
#define T_DIM   (N_BATCH * BLKSZ)   // 5888
#define CI      256
#define EPS_BN  1e-5f

#define TILE 64
#define BKK  16
#define LDT  68   // pad 64 -> 68 keeps float4 LDS reads 16B-aligned

// ---------------------------------------------------------------------------
// Kernel 1: BatchNorm(inference) + ReLU + transpose (N,C,46) -> feat (T, C)
// ---------------------------------------------------------------------------
__global__ __launch_bounds__(256) void bn_relu_kernel(
    const float* __restrict__ ori, const float* __restrict__ gamma,
    const float* __restrict__ beta, const float* __restrict__ mean,
    const float* __restrict__ var, float* __restrict__ feat)
{
    int idx = blockIdx.x * 256 + threadIdx.x;   // idx = t*C + c
    if (idx >= T_DIM * C_DIM) return;
    int c = idx & (C_DIM - 1);
    int t = idx >> 9;                 // / 512
    int n = t / BLKSZ, b = t - n * BLKSZ;
    float inv = gamma[c] / sqrtf(var[c] + EPS_BN);
    float v = ori[((size_t)n * C_DIM + c) * BLKSZ + b] * inv + (beta[c] - mean[c] * inv);
    feat[idx] = fmaxf(v, 0.0f);
}

// ---------------------------------------------------------------------------
// Generic 64x64-tile fp32 GEMM.
//  BNT=true : C = A(MxK) * B^T   with B given as (Nn x K) row-major
//  BNT=false: C = A(MxK) * B     with B given as (K x Nn) row-major
//  EPI: 0 = plain store, 1 = +bias, 2 = +bias + ori^T add (final output),
//       3 = atomicAdd (split-K accumulate)
// All of M, Nn divisible by 64; K divisible by 16 (by construction here).
// ---------------------------------------------------------------------------
template <int EPI, bool BNT>
__global__ __launch_bounds__(256) void gemm64(
    const float* __restrict__ A, const float* __restrict__ B,
    const float* __restrict__ bias, float* __restrict__ Cout,
    int M, int Nn, int K, int nsplit, const float* __restrict__ ori)
{
    __shared__ float As[BKK][LDT];
    __shared__ float Bs[BKK][LDT];
    const int tid = threadIdx.x;
    const int tx = tid & 15, ty = tid >> 4;
    const int m0 = blockIdx.y * TILE, n0 = blockIdx.x * TILE;

    const int ktotal = K / BKK;
    const int kper = ktotal / nsplit;
    const int kt0 = blockIdx.z * kper, kt1 = kt0 + kper;

    // staging load indices
    const int a_r = tid >> 2, a_c = (tid & 3) * 4;   // 64 rows x 16 k
    const int b_k = tid >> 4, b_n4 = (tid & 15) * 4; // 16 k x 64 n (NN case)

    float acc[4][4] = {};

    for (int kt = kt0; kt < kt1; ++kt) {
        const int k0 = kt * BKK;
        float4 va = *(const float4*)(A + (size_t)(m0 + a_r) * K + k0 + a_c);
        As[a_c + 0][a_r] = va.x; As[a_c + 1][a_r] = va.y;
        As[a_c + 2][a_r] = va.z; As[a_c + 3][a_r] = va.w;
        if (BNT) {
            float4 vb = *(const float4*)(B + (size_t)(n0 + a_r) * K + k0 + a_c);
            Bs[a_c + 0][a_r] = vb.x; Bs[a_c + 1][a_r] = vb.y;
            Bs[a_c + 2][a_r] = vb.z; Bs[a_c + 3][a_r] = vb.w;
        } else {
            float4 vb = *(const float4*)(B + (size_t)(k0 + b_k) * Nn + n0 + b_n4);
            *(float4*)(&Bs[b_k][b_n4]) = vb;
        }
        __syncthreads();
        #pragma unroll
        for (int kk = 0; kk < BKK; ++kk) {
            float4 a4 = *(const float4*)(&As[kk][ty * 4]);
            float4 b4 = *(const float4*)(&Bs[kk][tx * 4]);
            float av[4] = {a4.x, a4.y, a4.z, a4.w};
            float bv[4] = {b4.x, b4.y, b4.z, b4.w};
            #pragma unroll
            for (int i = 0; i < 4; ++i)
                #pragma unroll
                for (int j = 0; j < 4; ++j)
                    acc[i][j] += av[i] * bv[j];
        }
        __syncthreads();
    }

    // epilogue: thread covers rows m0+ty*4+i, cols n0+tx*4+j
    #pragma unroll
    for (int i = 0; i < 4; ++i) {
        const int m = m0 + ty * 4 + i;
        if (EPI == 3) {
            #pragma unroll
            for (int j = 0; j < 4; ++j)
                atomicAdd(&Cout[(size_t)m * Nn + n0 + tx * 4 + j], acc[i][j]);
        } else {
            float r[4];
            #pragma unroll
            for (int j = 0; j < 4; ++j) {
                const int n = n0 + tx * 4 + j;
                float v = acc[i][j];
                if (EPI >= 1) v += bias[n];
                if (EPI == 2) {
                    const int nb = m / BLKSZ, bb = m - nb * BLKSZ;
                    v += ori[((size_t)nb * C_DIM + n) * BLKSZ + bb];
                }
                r[j] = v;
            }
            *(float4*)(&Cout[(size_t)m * Nn + n0 + tx * 4]) =
                make_float4(r[0], r[1], r[2], r[3]);
        }
    }
}

// ---------------------------------------------------------------------------
// In-place masked row softmax over P (T_DIM x T_DIM).
// Row r: cols in [rb0, rb0+46) are masked (ref sets them to -1000 -> exp
// underflows to exactly 0 in fp32, so we write 0 there).
// 5888 = 23 * 256 -> exactly 23 strided iters per thread.
// ---------------------------------------------------------------------------
__global__ __launch_bounds__(256) void softmax_kernel(float* __restrict__ P)
{
    __shared__ float srow[T_DIM];
    __shared__ float redm[4];
    __shared__ float reds[4];
    const int r = blockIdx.x;
    const int tid = threadIdx.x;
    const int rb0 = (r / BLKSZ) * BLKSZ, rb1 = rb0 + BLKSZ;
    float* row = P + (size_t)r * T_DIM;

    float lmax = -1e30f;
    for (int c = tid; c < T_DIM; c += 256) {
        float v = row[c];
        srow[c] = v;
        if (c < rb0 || c >= rb1) lmax = fmaxf(lmax, v);
    }
    #pragma unroll
    for (int off = 32; off; off >>= 1) lmax = fmaxf(lmax, __shfl_down(lmax, off));
    if ((tid & 63) == 0) redm[tid >> 6] = lmax;
    __syncthreads();
    const float m = fmaxf(fmaxf(redm[0], redm[1]), fmaxf(redm[2], redm[3]));

    float lsum = 0.0f;
    for (int c = tid; c < T_DIM; c += 256) {
        if (c < rb0 || c >= rb1) {
            float e = expf(srow[c] - m);
            srow[c] = e;
            lsum += e;
        } else {
            srow[c] = 0.0f;
        }
    }
    #pragma unroll
    for (int off = 32; off; off >>= 1) lsum += __shfl_down(lsum, off);
    if ((tid & 63) == 0) reds[tid >> 6] = lsum;
    __syncthreads();
    const float invZ = 1.0f / (reds[0] + reds[1] + reds[2] + reds[3]);

    for (int c = tid; c < T_DIM; c += 256) row[c] = srow[c] * invZ;
}

// ---------------------------------------------------------------------------
extern "C" void kernel_launch(void* const* d_in, const int* in_sizes, int n_in,
                              void* d_out, int out_size, void* d_ws, size_t ws_size,
                              hipStream_t stream)
{
    const float* ori     = (const float*)d_in[0];
    const float* gamma   = (const float*)d_in[1];
    const float* beta    = (const float*)d_in[2];
    const float* mean    = (const float*)d_in[3];
    const float* var     = (const float*)d_in[4];
    const float* theta_w = (const float*)d_in[5];
    const float* theta_b = (const float*)d_in[6];
    const float* phi_w   = (const float*)d_in[7];
    const float* phi_b   = (const float*)d_in[8];
    const float* g_w     = (const float*)d_in[9];
    const float* g_b     = (const float*)d_in[10];
    const float* W_w     = (const float*)d_in[11];
    const float* W_b     = (const float*)d_in[12];

    float* out = (float*)d_out;                    // att_fea (T, C) then f_div_C (T, T)
    float* P   = out + (size_t)T_DIM * C_DIM;      // raw scores -> softmax in place

    float* feat = (float*)d_ws;                    // (T, C)
    float* xth  = feat + (size_t)T_DIM * C_DIM;    // (T, CI)
    float* xph  = xth  + (size_t)T_DIM * CI;
    float* gx   = xph  + (size_t)T_DIM * CI;
    float* yb   = gx   + (size_t)T_DIM * CI;       // (T, CI)

    // 1) BN + ReLU + transpose
    bn_relu_kernel<<<(T_DIM * C_DIM) / 256, 256, 0, stream>>>(
        ori, gamma, beta, mean, var, feat);

    // 2) projections: x = feat @ w.T + b   (M=5888, N=256, K=512)
    dim3 gproj(CI / TILE, T_DIM / TILE, 1);
    gemm64<1, true><<<gproj, 256, 0, stream>>>(feat, theta_w, theta_b, xth,
                                               T_DIM, CI, C_DIM, 1, nullptr);
    gemm64<1, true><<<gproj, 256, 0, stream>>>(feat, phi_w, phi_b, xph,
                                               T_DIM, CI, C_DIM, 1, nullptr);
    gemm64<1, true><<<gproj, 256, 0, stream>>>(feat, g_w, g_b, gx,
                                               T_DIM, CI, C_DIM, 1, nullptr);

    // 3) scores: P = x_theta @ x_phi^T   (M=N=5888, K=256), raw into d_out
    dim3 gattn(T_DIM / TILE, T_DIM / TILE, 1);
    gemm64<0, true><<<gattn, 256, 0, stream>>>(xth, xph, nullptr, P,
                                               T_DIM, T_DIM, CI, 1, nullptr);

    // 4) masked softmax in place -> f_div_C
    softmax_kernel<<<T_DIM, 256, 0, stream>>>(P);

    // 5) y = P @ g_x   (M=5888, N=256, K=5888), split-K=8 with atomics
    hipMemsetAsync(yb, 0, (size_t)T_DIM * CI * sizeof(float), stream);
    dim3 gy(CI / TILE, T_DIM / TILE, 8);
    gemm64<3, false><<<gy, 256, 0, stream>>>(P, gx, nullptr, yb,
                                             T_DIM, CI, T_DIM, 8, nullptr);

    // 6) att_fea = ori^T + y @ W_w^T + W_b   (M=5888, N=512, K=256)
    dim3 gfin(C_DIM / TILE, T_DIM / TILE, 1);
    gemm64<2, true><<<gfin, 256, 0, stream>>>(yb, W_w, W_b, out,
                                              T_DIM, C_DIM, CI, 1, ori);
}

// Round 2
// 426.785 us; speedup vs baseline: 2.0624x; 2.0624x over previous
//
#include <hip/hip_runtime.h>
#include <math.h>

#define N_BATCH 128
#define C_DIM   512
#define BLKSZ   46
#define T_DIM   (N_BATCH * BLKSZ)   // 5888
#define CI      256
#define EPS_BN  1e-5f

typedef __attribute__((ext_vector_type(8))) short bf16x8;
typedef __attribute__((ext_vector_type(4))) float f32x4;

__device__ __forceinline__ short f2bf(float f) {
    union { float f; unsigned u; } v; v.f = f;
    unsigned r = v.u + 0x7fffu + ((v.u >> 16) & 1u);
    return (short)(r >> 16);
}

__device__ __forceinline__ void gload16(const void* g, void* l) {
    __builtin_amdgcn_global_load_lds((__attribute__((address_space(1))) void*)g,
                                     (__attribute__((address_space(3))) void*)l,
                                     16, 0, 0);
}

// ---------------------------------------------------------------------------
// BN(inference)+ReLU+transpose: ori (N,C,46) fp32 -> feat (T, C) bf16.
// Block = (c-half, n): coalesced fp32 reads, LDS transpose, coalesced bf16 writes.
// ---------------------------------------------------------------------------
__global__ __launch_bounds__(256) void bn_relu_kernel(
    const float* __restrict__ ori, const float* __restrict__ gamma,
    const float* __restrict__ beta, const float* __restrict__ mean,
    const float* __restrict__ var, short* __restrict__ feat)
{
    __shared__ short tile[256 * BLKSZ];
    const int n = blockIdx.y;
    const int c0 = blockIdx.x * 256;
    const int tid = threadIdx.x;
    for (int i = tid; i < 256 * BLKSZ; i += 256) {
        int cl = i / BLKSZ, b = i - cl * BLKSZ;
        int c = c0 + cl;
        float inv = gamma[c] * rsqrtf(var[c] + EPS_BN);
        float v = ori[((size_t)n * C_DIM + c) * BLKSZ + b] * inv + (beta[c] - mean[c] * inv);
        tile[cl * BLKSZ + b] = f2bf(fmaxf(v, 0.0f));
    }
    __syncthreads();
    for (int i = tid; i < BLKSZ * 256; i += 256) {
        int b = i >> 8, cl = i & 255;
        feat[(size_t)(n * BLKSZ + b) * C_DIM + c0 + cl] = tile[cl * BLKSZ + b];
    }
}

// ---------------------------------------------------------------------------
// Convert the 4 weight matrices (each 256*512 = 131072 elems) fp32 -> bf16.
// ---------------------------------------------------------------------------
__global__ __launch_bounds__(256) void cvt4_kernel(
    const float* __restrict__ a, const float* __restrict__ b,
    const float* __restrict__ c, const float* __restrict__ d,
    short* __restrict__ oa, short* __restrict__ ob,
    short* __restrict__ oc, short* __restrict__ od)
{
    const int i = blockIdx.x * 256 + threadIdx.x;  // float4 index, 32768 total
    const float* src[4] = {a, b, c, d};
    short* dst[4] = {oa, ob, oc, od};
    #pragma unroll
    for (int m = 0; m < 4; ++m) {
        float4 v = *(const float4*)(src[m] + (size_t)i * 4);
        short4 t = make_short4(f2bf(v.x), f2bf(v.y), f2bf(v.z), f2bf(v.w));
        *(short4*)(dst[m] + (size_t)i * 4) = t;
    }
}

// ---------------------------------------------------------------------------
// NT bf16 MFMA GEMM: C(M,Nn) = A(M,K) @ B(Nn,K)^T.  128x128 tile, BK=32,
// 4 waves each doing a 64x64 block of 4x4 16x16x32 MFMAs.
// ACVT=true: A is fp32 in global, converted to bf16 during LDS staging (PV).
// EPI: 0 raw fp32 store; 1 bf16 + col-bias; 2 bf16 + row-bias;
//      3 fp32 split-K partial at Cout + bz*M*Nn; 4 fp32 + col-bias + ori^T.
// M,Nn % 128 == 0; K % (32*nsplit) == 0.
// ---------------------------------------------------------------------------
template <int EPI, bool ACVT>
__global__ __launch_bounds__(256, 2) void gemm_nt(
    const void* __restrict__ Avoid, const short* __restrict__ B,
    const float* __restrict__ bias, void* __restrict__ Cvoid,
    int M, int Nn, int K, int nsplit, const float* __restrict__ ori)
{
    __shared__ short As[128 * 32];
    __shared__ short Bs[128 * 32];
    const int tid = threadIdx.x;
    const int w = tid >> 6, lane = tid & 63;
    const int m0 = blockIdx.y * 128, n0 = blockIdx.x * 128;
    const int wr = w >> 1, wc = w & 1;

    const int ksteps = K / 32 / nsplit;
    const int kt0 = blockIdx.z * ksteps;

    f32x4 acc[4][4] = {};

    const int rA = w * 16 + (lane >> 2);   // staging row (this wave, issue q=0)
    const int cA = (lane & 3) * 8;         // staging k-offset (elements)
    const short* Ab = (const short*)Avoid;
    const float* Af = (const float*)Avoid;

    for (int kt = kt0; kt < kt0 + ksteps; ++kt) {
        const int k0 = kt * 32;
        if (!ACVT) {
            gload16(Ab + (size_t)(m0 + rA) * K + k0 + cA, &As[rA * 32 + cA]);
            gload16(Ab + (size_t)(m0 + rA + 64) * K + k0 + cA, &As[(rA + 64) * 32 + cA]);
        } else {
            const int ar = tid >> 1, ac = (tid & 1) * 16;
            const float* src = Af + (size_t)(m0 + ar) * K + k0 + ac;
            short tmp[16] __attribute__((aligned(16)));
            #pragma unroll
            for (int q = 0; q < 4; ++q) {
                float4 v = *(const float4*)(src + q * 4);
                tmp[q * 4 + 0] = f2bf(v.x); tmp[q * 4 + 1] = f2bf(v.y);
                tmp[q * 4 + 2] = f2bf(v.z); tmp[q * 4 + 3] = f2bf(v.w);
            }
            *(bf16x8*)&As[ar * 32 + ac]     = *(bf16x8*)&tmp[0];
            *(bf16x8*)&As[ar * 32 + ac + 8] = *(bf16x8*)&tmp[8];
        }
        gload16(B + (size_t)(n0 + rA) * K + k0 + cA, &Bs[rA * 32 + cA]);
        gload16(B + (size_t)(n0 + rA + 64) * K + k0 + cA, &Bs[(rA + 64) * 32 + cA]);
        __syncthreads();

        bf16x8 af[4], bf[4];
        #pragma unroll
        for (int i = 0; i < 4; ++i)
            af[i] = *(bf16x8*)&As[(wr * 64 + i * 16 + (lane & 15)) * 32 + (lane >> 4) * 8];
        #pragma unroll
        for (int j = 0; j < 4; ++j)
            bf[j] = *(bf16x8*)&Bs[(wc * 64 + j * 16 + (lane & 15)) * 32 + (lane >> 4) * 8];
        #pragma unroll
        for (int i = 0; i < 4; ++i)
            #pragma unroll
            for (int j = 0; j < 4; ++j)
                acc[i][j] = __builtin_amdgcn_mfma_f32_16x16x32_bf16(af[i], bf[j], acc[i][j], 0, 0, 0);
        __syncthreads();
    }

    // epilogue: C/D layout col=lane&15, row=(lane>>4)*4+reg  [m89-verified]
    const int col = lane & 15, rowq = lane >> 4;
    #pragma unroll
    for (int i = 0; i < 4; ++i) {
        #pragma unroll
        for (int j = 0; j < 4; ++j) {
            #pragma unroll
            for (int r = 0; r < 4; ++r) {
                const int grow = m0 + wr * 64 + i * 16 + rowq * 4 + r;
                const int gcol = n0 + wc * 64 + j * 16 + col;
                const float v = acc[i][j][r];
                if (EPI == 0) {
                    ((float*)Cvoid)[(size_t)grow * Nn + gcol] = v;
                } else if (EPI == 1) {
                    ((short*)Cvoid)[(size_t)grow * Nn + gcol] = f2bf(v + bias[gcol]);
                } else if (EPI == 2) {
                    ((short*)Cvoid)[(size_t)grow * Nn + gcol] = f2bf(v + bias[grow]);
                } else if (EPI == 3) {
                    ((float*)Cvoid)[(size_t)blockIdx.z * M * Nn + (size_t)grow * Nn + gcol] = v;
                } else {
                    const int nb = grow / BLKSZ, bb = grow - nb * BLKSZ;
                    ((float*)Cvoid)[(size_t)grow * Nn + gcol] =
                        v + bias[gcol] + ori[((size_t)nb * C_DIM + gcol) * BLKSZ + bb];
                }
            }
        }
    }
}

// ---------------------------------------------------------------------------
// In-place masked row softmax over P (T_DIM x T_DIM) fp32.
// ---------------------------------------------------------------------------
__global__ __launch_bounds__(256) void softmax_kernel(float* __restrict__ P)
{
    __shared__ float srow[T_DIM];
    __shared__ float redm[4];
    __shared__ float reds[4];
    const int r = blockIdx.x;
    const int tid = threadIdx.x;
    const int rb0 = (r / BLKSZ) * BLKSZ, rb1 = rb0 + BLKSZ;
    float* row = P + (size_t)r * T_DIM;

    float lmax = -1e30f;
    for (int c = tid; c < T_DIM; c += 256) {
        float v = row[c];
        srow[c] = v;
        if (c < rb0 || c >= rb1) lmax = fmaxf(lmax, v);
    }
    #pragma unroll
    for (int off = 32; off; off >>= 1) lmax = fmaxf(lmax, __shfl_down(lmax, off));
    if ((tid & 63) == 0) redm[tid >> 6] = lmax;
    __syncthreads();
    const float m = fmaxf(fmaxf(redm[0], redm[1]), fmaxf(redm[2], redm[3]));

    float lsum = 0.0f;
    for (int c = tid; c < T_DIM; c += 256) {
        if (c < rb0 || c >= rb1) {
            float e = expf(srow[c] - m);
            srow[c] = e;
            lsum += e;
        } else {
            srow[c] = 0.0f;
        }
    }
    #pragma unroll
    for (int off = 32; off; off >>= 1) lsum += __shfl_down(lsum, off);
    if ((tid & 63) == 0) reds[tid >> 6] = lsum;
    __syncthreads();
    const float invZ = 1.0f / (reds[0] + reds[1] + reds[2] + reds[3]);

    for (int c = tid; c < T_DIM; c += 256) row[c] = srow[c] * invZ;
}

// ---------------------------------------------------------------------------
// Reduce split-K partials (2, T, CI) fp32 -> y (T, CI) bf16.
// ---------------------------------------------------------------------------
__global__ __launch_bounds__(256) void reduce_y_kernel(
    const float* __restrict__ part, short* __restrict__ y)
{
    const size_t i = (size_t)blockIdx.x * 256 + threadIdx.x;  // float4 index
    float4 v0 = *(const float4*)(part + i * 4);
    float4 v1 = *(const float4*)(part + (size_t)T_DIM * CI + i * 4);
    short4 t = make_short4(f2bf(v0.x + v1.x), f2bf(v0.y + v1.y),
                           f2bf(v0.z + v1.z), f2bf(v0.w + v1.w));
    *(short4*)(y + i * 4) = t;
}

// ---------------------------------------------------------------------------
extern "C" void kernel_launch(void* const* d_in, const int* in_sizes, int n_in,
                              void* d_out, int out_size, void* d_ws, size_t ws_size,
                              hipStream_t stream)
{
    const float* ori     = (const float*)d_in[0];
    const float* gamma   = (const float*)d_in[1];
    const float* beta    = (const float*)d_in[2];
    const float* mean    = (const float*)d_in[3];
    const float* var     = (const float*)d_in[4];
    const float* theta_w = (const float*)d_in[5];
    const float* theta_b = (const float*)d_in[6];
    const float* phi_w   = (const float*)d_in[7];
    const float* phi_b   = (const float*)d_in[8];
    const float* g_w     = (const float*)d_in[9];
    const float* g_b     = (const float*)d_in[10];
    const float* W_w     = (const float*)d_in[11];
    const float* W_b     = (const float*)d_in[12];

    float* out = (float*)d_out;                    // att_fea (T, C), then f_div_C (T, T)
    float* P   = out + (size_t)T_DIM * C_DIM;      // raw scores -> softmax in place

    char* wsb = (char*)d_ws;
    short* feat = (short*)wsb;  wsb += (size_t)T_DIM * C_DIM * 2;
    short* xth  = (short*)wsb;  wsb += (size_t)T_DIM * CI * 2;
    short* xph  = (short*)wsb;  wsb += (size_t)T_DIM * CI * 2;
    short* gxT  = (short*)wsb;  wsb += (size_t)T_DIM * CI * 2;   // (CI, T)
    short* wth  = (short*)wsb;  wsb += (size_t)CI * C_DIM * 2;
    short* wph  = (short*)wsb;  wsb += (size_t)CI * C_DIM * 2;
    short* wg   = (short*)wsb;  wsb += (size_t)CI * C_DIM * 2;
    short* wW   = (short*)wsb;  wsb += (size_t)C_DIM * CI * 2;
    float* ypart= (float*)wsb;  wsb += (size_t)2 * T_DIM * CI * 4;
    short* ybf  = (short*)wsb;  wsb += (size_t)T_DIM * CI * 2;

    // 1) BN + ReLU + transpose -> feat bf16;  weights -> bf16
    bn_relu_kernel<<<dim3(2, 128), 256, 0, stream>>>(ori, gamma, beta, mean, var, feat);
    cvt4_kernel<<<128, 256, 0, stream>>>(theta_w, phi_w, g_w, W_w, wth, wph, wg, wW);

    // 2) xth/xph = feat @ w^T + b  (M=T, Nn=CI, K=C), bf16 out
    gemm_nt<1, false><<<dim3(CI / 128, T_DIM / 128), 256, 0, stream>>>(
        feat, wth, theta_b, xth, T_DIM, CI, C_DIM, 1, nullptr);
    gemm_nt<1, false><<<dim3(CI / 128, T_DIM / 128), 256, 0, stream>>>(
        feat, wph, phi_b, xph, T_DIM, CI, C_DIM, 1, nullptr);

    // 3) gxT = wg @ feat^T + g_b(row)  (M=CI, Nn=T, K=C), bf16 out (transposed g_x)
    gemm_nt<2, false><<<dim3(T_DIM / 128, CI / 128), 256, 0, stream>>>(
        wg, feat, g_b, gxT, CI, T_DIM, C_DIM, 1, nullptr);

    // 4) P = xth @ xph^T  (M=Nn=T, K=CI), raw fp32 into d_out
    gemm_nt<0, false><<<dim3(T_DIM / 128, T_DIM / 128), 256, 0, stream>>>(
        xth, xph, nullptr, P, T_DIM, T_DIM, CI, 1, nullptr);

    // 5) masked softmax in place -> f_div_C
    softmax_kernel<<<T_DIM, 256, 0, stream>>>(P);

    // 6) ypart[z] = P(fp32, converted on stage) @ gxT^T  split-K=2
    gemm_nt<3, true><<<dim3(CI / 128, T_DIM / 128, 2), 256, 0, stream>>>(
        P, gxT, nullptr, ypart, T_DIM, CI, T_DIM, 2, nullptr);
    reduce_y_kernel<<<(T_DIM * CI / 4) / 256, 256, 0, stream>>>(ypart, ybf);

    // 7) att_fea = y @ wW^T + W_b + ori^T  (M=T, Nn=C, K=CI), fp32 out
    gemm_nt<4, false><<<dim3(C_DIM / 128, T_DIM / 128), 256, 0, stream>>>(
        ybf, wW, W_b, out, T_DIM, C_DIM, CI, 1, ori);
}

// Round 3
// 365.916 us; speedup vs baseline: 2.4055x; 1.1663x over previous
//
#include <hip/hip_runtime.h>
#include <math.h>

#define N_BATCH 128
#define C_DIM   512
#define BLKSZ   46
#define T_DIM   (N_BATCH * BLKSZ)   // 5888
#define CI      256
#define EPS_BN  1e-5f

typedef __attribute__((ext_vector_type(8))) short bf16x8;
typedef __attribute__((ext_vector_type(4))) float f32x4;

__device__ __forceinline__ short f2bf(float f) {
    union { float f; unsigned u; } v; v.f = f;
    unsigned r = v.u + 0x7fffu + ((v.u >> 16) & 1u);
    return (short)(r >> 16);
}

__device__ __forceinline__ void gload16(const void* g, void* l) {
    __builtin_amdgcn_global_load_lds((__attribute__((address_space(1))) void*)g,
                                     (__attribute__((address_space(3))) void*)l,
                                     16, 0, 0);
}

// ---------------------------------------------------------------------------
// BN(inference)+ReLU+transpose: ori (N,C,46) fp32 -> feat (T, C) bf16.
// ---------------------------------------------------------------------------
__global__ __launch_bounds__(256) void bn_relu_kernel(
    const float* __restrict__ ori, const float* __restrict__ gamma,
    const float* __restrict__ beta, const float* __restrict__ mean,
    const float* __restrict__ var, short* __restrict__ feat)
{
    __shared__ short tile[256 * BLKSZ];
    const int n = blockIdx.y;
    const int c0 = blockIdx.x * 256;
    const int tid = threadIdx.x;
    for (int i = tid; i < 256 * BLKSZ; i += 256) {
        int cl = i / BLKSZ, b = i - cl * BLKSZ;
        int c = c0 + cl;
        float inv = gamma[c] * rsqrtf(var[c] + EPS_BN);
        float v = ori[((size_t)n * C_DIM + c) * BLKSZ + b] * inv + (beta[c] - mean[c] * inv);
        tile[cl * BLKSZ + b] = f2bf(fmaxf(v, 0.0f));
    }
    __syncthreads();
    for (int i = tid; i < BLKSZ * 256; i += 256) {
        int b = i >> 8, cl = i & 255;
        feat[(size_t)(n * BLKSZ + b) * C_DIM + c0 + cl] = tile[cl * BLKSZ + b];
    }
}

// ---------------------------------------------------------------------------
// Convert weights fp32->bf16: theta_w+phi_w packed into wcat (512 x 512),
// plus wg, wW. Block 0 additionally packs bcat = [theta_b; phi_b] (fp32).
// ---------------------------------------------------------------------------
__global__ __launch_bounds__(256) void cvt_kernel(
    const float* __restrict__ thw, const float* __restrict__ phw,
    const float* __restrict__ gw, const float* __restrict__ Ww,
    const float* __restrict__ thb, const float* __restrict__ phb,
    short* __restrict__ wcat, short* __restrict__ wg,
    short* __restrict__ wW, float* __restrict__ bcat)
{
    const int i = blockIdx.x * 256 + threadIdx.x;  // float4 index, 32768 per mat
    const float* src[4] = {thw, phw, gw, Ww};
    short* dst[4] = {wcat, wcat + 256 * 512, wg, wW};
    #pragma unroll
    for (int m = 0; m < 4; ++m) {
        float4 v = *(const float4*)(src[m] + (size_t)i * 4);
        short4 t = make_short4(f2bf(v.x), f2bf(v.y), f2bf(v.z), f2bf(v.w));
        *(short4*)(dst[m] + (size_t)i * 4) = t;
    }
    if (blockIdx.x == 0) {
        bcat[threadIdx.x] = thb[threadIdx.x];
        bcat[threadIdx.x + 256] = phb[threadIdx.x];
    }
}

// ---------------------------------------------------------------------------
// NT bf16 MFMA GEMM: C(M,Nn) = A(M,K) @ B(Nn,K)^T, BMxBN tile, BK=32,
// 4 waves (BM/64 x BN/64 arrangement of 64x64 wave blocks), 256 threads.
// lda/ldb = row strides (elements) of A and B.
// ACVT=true: A is fp32 in global, converted to bf16 during LDS staging.
// EPI: 0 raw fp32 store; 1 bf16 + col-bias; 2 bf16 + row-bias;
//      3 fp32 split-K partial at C + bz*M*Nn; 4 fp32 + col-bias + ori^T add.
// ---------------------------------------------------------------------------
template <int EPI, bool ACVT, int BM, int BN>
__global__ __launch_bounds__(256, 2) void gemm_nt(
    const void* __restrict__ Avoid, const short* __restrict__ B,
    const float* __restrict__ bias, void* __restrict__ Cvoid,
    int M, int Nn, int K, int lda, int ldb, int nsplit,
    const float* __restrict__ ori)
{
    constexpr int NWC = BN / 64;
    __shared__ short As[BM * 32];
    __shared__ short Bs[BN * 32];
    const int tid = threadIdx.x;
    const int w = tid >> 6, lane = tid & 63;
    const int m0 = blockIdx.y * BM, n0 = blockIdx.x * BN;
    const int wr = w / NWC, wc = w % NWC;

    const int kper = K / 32 / nsplit;
    const int kt0 = blockIdx.z * kper, kt1 = kt0 + kper;

    f32x4 acc[4][4] = {};

    const int sr = tid >> 2;          // 0..63
    const int sc = (tid & 3) * 8;     // k offset of 16B chunk
    const short* Ab = (const short*)Avoid;
    const float* Af = (const float*)Avoid;

    for (int kt = kt0; kt < kt1; ++kt) {
        const int k0 = kt * 32;
        if (!ACVT) {
            #pragma unroll
            for (int p = 0; p < BM / 64; ++p)
                gload16(Ab + (size_t)(m0 + p * 64 + sr) * lda + k0 + sc,
                        &As[(p * 64 + sr) * 32 + sc]);
        } else {
            constexpr int EPT = BM / 8;     // fp32 elems per thread
            constexpr int TPR = 32 / EPT;   // threads per row
            const int ar = tid / TPR;
            const int ac = (tid % TPR) * EPT;
            const float* src = Af + (size_t)(m0 + ar) * lda + k0 + ac;
            short tmp[EPT] __attribute__((aligned(16)));
            #pragma unroll
            for (int q = 0; q < EPT / 4; ++q) {
                float4 v = *(const float4*)(src + q * 4);
                tmp[q * 4 + 0] = f2bf(v.x); tmp[q * 4 + 1] = f2bf(v.y);
                tmp[q * 4 + 2] = f2bf(v.z); tmp[q * 4 + 3] = f2bf(v.w);
            }
            #pragma unroll
            for (int q = 0; q < EPT / 8; ++q)
                *(bf16x8*)&As[ar * 32 + ac + q * 8] = *(bf16x8*)&tmp[q * 8];
        }
        #pragma unroll
        for (int p = 0; p < BN / 64; ++p)
            gload16(B + (size_t)(n0 + p * 64 + sr) * ldb + k0 + sc,
                    &Bs[(p * 64 + sr) * 32 + sc]);
        __syncthreads();

        bf16x8 af[4], bfr[4];
        #pragma unroll
        for (int i = 0; i < 4; ++i)
            af[i] = *(bf16x8*)&As[(wr * 64 + i * 16 + (lane & 15)) * 32 + (lane >> 4) * 8];
        #pragma unroll
        for (int j = 0; j < 4; ++j)
            bfr[j] = *(bf16x8*)&Bs[(wc * 64 + j * 16 + (lane & 15)) * 32 + (lane >> 4) * 8];
        #pragma unroll
        for (int i = 0; i < 4; ++i)
            #pragma unroll
            for (int j = 0; j < 4; ++j)
                acc[i][j] = __builtin_amdgcn_mfma_f32_16x16x32_bf16(af[i], bfr[j], acc[i][j], 0, 0, 0);
        __syncthreads();
    }

    // epilogue: C/D layout col=lane&15, row=(lane>>4)*4+reg  [m89-verified]
    const int col = lane & 15, rowq = lane >> 4;
    #pragma unroll
    for (int i = 0; i < 4; ++i) {
        #pragma unroll
        for (int j = 0; j < 4; ++j) {
            #pragma unroll
            for (int r = 0; r < 4; ++r) {
                const int grow = m0 + wr * 64 + i * 16 + rowq * 4 + r;
                const int gcol = n0 + wc * 64 + j * 16 + col;
                const float v = acc[i][j][r];
                if (EPI == 0) {
                    ((float*)Cvoid)[(size_t)grow * Nn + gcol] = v;
                } else if (EPI == 1) {
                    ((short*)Cvoid)[(size_t)grow * Nn + gcol] = f2bf(v + bias[gcol]);
                } else if (EPI == 2) {
                    ((short*)Cvoid)[(size_t)grow * Nn + gcol] = f2bf(v + bias[grow]);
                } else if (EPI == 3) {
                    ((float*)Cvoid)[(size_t)blockIdx.z * M * Nn + (size_t)grow * Nn + gcol] = v;
                } else {
                    const int nb = grow / BLKSZ, bb = grow - nb * BLKSZ;
                    ((float*)Cvoid)[(size_t)grow * Nn + gcol] =
                        v + bias[gcol] + ori[((size_t)nb * C_DIM + gcol) * BLKSZ + bb];
                }
            }
        }
    }
}

// ---------------------------------------------------------------------------
// In-place masked row softmax over P (T_DIM x T_DIM) fp32.
// ---------------------------------------------------------------------------
__global__ __launch_bounds__(256) void softmax_kernel(float* __restrict__ P)
{
    __shared__ float srow[T_DIM];
    __shared__ float redm[4];
    __shared__ float reds[4];
    const int r = blockIdx.x;
    const int tid = threadIdx.x;
    const int rb0 = (r / BLKSZ) * BLKSZ, rb1 = rb0 + BLKSZ;
    float* row = P + (size_t)r * T_DIM;

    float lmax = -1e30f;
    for (int c = tid; c < T_DIM; c += 256) {
        float v = row[c];
        srow[c] = v;
        if (c < rb0 || c >= rb1) lmax = fmaxf(lmax, v);
    }
    #pragma unroll
    for (int off = 32; off; off >>= 1) lmax = fmaxf(lmax, __shfl_down(lmax, off));
    if ((tid & 63) == 0) redm[tid >> 6] = lmax;
    __syncthreads();
    const float m = fmaxf(fmaxf(redm[0], redm[1]), fmaxf(redm[2], redm[3]));

    float lsum = 0.0f;
    for (int c = tid; c < T_DIM; c += 256) {
        if (c < rb0 || c >= rb1) {
            float e = expf(srow[c] - m);
            srow[c] = e;
            lsum += e;
        } else {
            srow[c] = 0.0f;
        }
    }
    #pragma unroll
    for (int off = 32; off; off >>= 1) lsum += __shfl_down(lsum, off);
    if ((tid & 63) == 0) reds[tid >> 6] = lsum;
    __syncthreads();
    const float invZ = 1.0f / (reds[0] + reds[1] + reds[2] + reds[3]);

    for (int c = tid; c < T_DIM; c += 256) row[c] = srow[c] * invZ;
}

// ---------------------------------------------------------------------------
// Reduce split-K partials (ns, T, CI) fp32 -> y (T, CI) bf16.
// ---------------------------------------------------------------------------
__global__ __launch_bounds__(256) void reduce_y_kernel(
    const float* __restrict__ part, short* __restrict__ y, int ns)
{
    const size_t i = (size_t)blockIdx.x * 256 + threadIdx.x;  // float4 index
    float4 s = *(const float4*)(part + i * 4);
    for (int z = 1; z < ns; ++z) {
        float4 v = *(const float4*)(part + (size_t)z * T_DIM * CI + i * 4);
        s.x += v.x; s.y += v.y; s.z += v.z; s.w += v.w;
    }
    short4 t = make_short4(f2bf(s.x), f2bf(s.y), f2bf(s.z), f2bf(s.w));
    *(short4*)(y + i * 4) = t;
}

// ---------------------------------------------------------------------------
extern "C" void kernel_launch(void* const* d_in, const int* in_sizes, int n_in,
                              void* d_out, int out_size, void* d_ws, size_t ws_size,
                              hipStream_t stream)
{
    const float* ori     = (const float*)d_in[0];
    const float* gamma   = (const float*)d_in[1];
    const float* beta    = (const float*)d_in[2];
    const float* mean    = (const float*)d_in[3];
    const float* var     = (const float*)d_in[4];
    const float* theta_w = (const float*)d_in[5];
    const float* theta_b = (const float*)d_in[6];
    const float* phi_w   = (const float*)d_in[7];
    const float* phi_b   = (const float*)d_in[8];
    const float* g_w     = (const float*)d_in[9];
    const float* g_b     = (const float*)d_in[10];
    const float* W_w     = (const float*)d_in[11];
    const float* W_b     = (const float*)d_in[12];

    float* out = (float*)d_out;                    // att_fea (T, C), then f_div_C (T, T)
    float* P   = out + (size_t)T_DIM * C_DIM;      // raw scores -> softmax in place

    char* wsb = (char*)d_ws;
    short* feat = (short*)wsb;  wsb += (size_t)T_DIM * C_DIM * 2;   // 6.03 MB
    short* xcat = (short*)wsb;  wsb += (size_t)T_DIM * 512 * 2;     // 6.03 MB (xth|xph)
    short* gxT  = (short*)wsb;  wsb += (size_t)CI * T_DIM * 2;      // 3.01 MB (CI, T)
    short* wcat = (short*)wsb;  wsb += (size_t)512 * C_DIM * 2;     // 0.52 MB
    short* wg   = (short*)wsb;  wsb += (size_t)CI * C_DIM * 2;
    short* wW   = (short*)wsb;  wsb += (size_t)C_DIM * CI * 2;
    float* bcat = (float*)wsb;  wsb += 512 * 4;
    short* ybf  = (short*)wsb;  wsb += (size_t)T_DIM * CI * 2;      // 3.01 MB
    float* ypart= (float*)wsb;                                      // ns * 6.03 MB

    const size_t base = (size_t)((char*)ypart - (char*)d_ws);
    const int ns = (ws_size >= base + 8u * T_DIM * CI * 4u) ? 8 : 4;

    // 1) BN + ReLU + transpose -> feat bf16; weights -> bf16 (+ packed bias)
    bn_relu_kernel<<<dim3(2, 128), 256, 0, stream>>>(ori, gamma, beta, mean, var, feat);
    cvt_kernel<<<128, 256, 0, stream>>>(theta_w, phi_w, g_w, W_w, theta_b, phi_b,
                                        wcat, wg, wW, bcat);

    // 2) xcat = feat @ wcat^T + bcat  (M=T, Nn=512, K=512) -> [xth | xph] bf16
    gemm_nt<1, false, 128, 128><<<dim3(4, T_DIM / 128), 256, 0, stream>>>(
        feat, wcat, bcat, xcat, T_DIM, 512, C_DIM, C_DIM, C_DIM, 1, nullptr);

    // 3) gxT = wg @ feat^T + g_b(row)  (M=CI, Nn=T, K=C) bf16
    gemm_nt<2, false, 128, 128><<<dim3(T_DIM / 128, CI / 128), 256, 0, stream>>>(
        wg, feat, g_b, gxT, CI, T_DIM, C_DIM, C_DIM, C_DIM, 1, nullptr);

    // 4) P = xth @ xph^T  (M=Nn=T, K=CI), strided slices of xcat, fp32 into d_out
    gemm_nt<0, false, 128, 128><<<dim3(T_DIM / 128, T_DIM / 128), 256, 0, stream>>>(
        xcat, xcat + CI, nullptr, P, T_DIM, T_DIM, CI, 512, 512, 1, nullptr);

    // 5) masked softmax in place -> f_div_C
    softmax_kernel<<<T_DIM, 256, 0, stream>>>(P);

    // 6) ypart[z] = P(fp32, staged-convert) @ gxT^T, split-K=ns, 64x256 tile
    gemm_nt<3, true, 64, 256><<<dim3(1, T_DIM / 64, ns), 256, 0, stream>>>(
        P, gxT, nullptr, ypart, T_DIM, CI, T_DIM, T_DIM, T_DIM, ns, nullptr);
    reduce_y_kernel<<<(T_DIM * CI / 4) / 256, 256, 0, stream>>>(ypart, ybf, ns);

    // 7) att_fea = y @ wW^T + W_b + ori^T  (M=T, Nn=C, K=CI), fp32 out
    gemm_nt<4, false, 128, 128><<<dim3(C_DIM / 128, T_DIM / 128), 256, 0, stream>>>(
        ybf, wW, W_b, out, T_DIM, C_DIM, CI, CI, CI, 1, ori);
}